// Round 1
// baseline (61.911 us; speedup 1.0000x reference)
//
#include <hip/hip_runtime.h>
#include <math.h>

// Hash-grid (instant-NGP style) trilinear interpolation, layer 8.
// T = 2^19 entries x F=2 floats; N = 2^21 points x 3 dims.
// RES = 16 * growth^8, growth = exp(ln(512/16)/15) = 2^(1/3) -> RES = 2^(20/3).
// Hash: (ix*1 ^ iy*2654435761 ^ iz*805459861) mod 2^19 -- int64 in the
// reference, but mod-2^19 makes uint32 arithmetic bit-exact (low bits of
// products and XORs agree).

#define HT_SIZE 524288u
#define HT_MASK (HT_SIZE - 1u)
#define PRIME_Y 2654435761u
#define PRIME_Z 805459861u
#define N_POINTS 2097152

__global__ __launch_bounds__(256) void hashgrid_interp_kernel(
    const float* __restrict__ X,
    const float* __restrict__ table,   // T x 2 floats
    float2* __restrict__ out,
    float scale)                        // (float)(RES - 1.0)
{
    int i = blockIdx.x * blockDim.x + threadIdx.x;
    if (i >= N_POINTS) return;

    float xs = X[3 * i + 0] * scale;
    float ys = X[3 * i + 1] * scale;
    float zs = X[3 * i + 2] * scale;

    float fx = floorf(xs), fy = floorf(ys), fz = floorf(zs);
    float wx = xs - fx,   wy = ys - fy,   wz = zs - fz;

    unsigned ix0 = (unsigned)(int)fx;
    unsigned iy0 = (unsigned)(int)fy;
    unsigned iz0 = (unsigned)(int)fz;
    unsigned ix1 = (unsigned)(int)ceilf(xs);
    unsigned iy1 = (unsigned)(int)ceilf(ys);
    unsigned iz1 = (unsigned)(int)ceilf(zs);

    unsigned hx0 = ix0;            // prime 1
    unsigned hx1 = ix1;
    unsigned hy0 = iy0 * PRIME_Y;
    unsigned hy1 = iy1 * PRIME_Y;
    unsigned hz0 = iz0 * PRIME_Z;
    unsigned hz1 = iz1 * PRIME_Z;

    const float2* tb = (const float2*)table;

    // corner c = (bx<<2) | (by<<1) | bz  (bit2 -> x uses ceil, etc.)
    float2 v0 = tb[(hx0 ^ hy0 ^ hz0) & HT_MASK];  // c=0: 000
    float2 v1 = tb[(hx0 ^ hy0 ^ hz1) & HT_MASK];  // c=1: z=1
    float2 v2 = tb[(hx0 ^ hy1 ^ hz0) & HT_MASK];  // c=2: y=1
    float2 v3 = tb[(hx0 ^ hy1 ^ hz1) & HT_MASK];  // c=3: y=1,z=1
    float2 v4 = tb[(hx1 ^ hy0 ^ hz0) & HT_MASK];  // c=4: x=1
    float2 v5 = tb[(hx1 ^ hy0 ^ hz1) & HT_MASK];  // c=5: x=1,z=1
    float2 v6 = tb[(hx1 ^ hy1 ^ hz0) & HT_MASK];  // c=6: x=1,y=1
    float2 v7 = tb[(hx1 ^ hy1 ^ hz1) & HT_MASK];  // c=7: 111

    float omx = 1.0f - wx, omy = 1.0f - wy, omz = 1.0f - wz;

    // p00 = lerp(v0, v4, wx); p01 = lerp(v1, v5, wx);
    // p10 = lerp(v2, v6, wx); p11 = lerp(v3, v7, wx);
    float p00x = v0.x * omx + v4.x * wx;
    float p00y = v0.y * omx + v4.y * wx;
    float p01x = v1.x * omx + v5.x * wx;
    float p01y = v1.y * omx + v5.y * wx;
    float p10x = v2.x * omx + v6.x * wx;
    float p10y = v2.y * omx + v6.y * wx;
    float p11x = v3.x * omx + v7.x * wx;
    float p11y = v3.y * omx + v7.y * wx;

    float p0x = p00x * omy + p10x * wy;
    float p0y = p00y * omy + p10y * wy;
    float p1x = p01x * omy + p11x * wy;
    float p1y = p01y * omy + p11y * wy;

    float2 r;
    r.x = p0x * omz + p1x * wz;
    r.y = p0y * omz + p1y * wz;
    out[i] = r;
}

extern "C" void kernel_launch(void* const* d_in, const int* in_sizes, int n_in,
                              void* d_out, int out_size, void* d_ws, size_t ws_size,
                              hipStream_t stream) {
    const float* X     = (const float*)d_in[0];
    const float* table = (const float*)d_in[1];
    float2* out = (float2*)d_out;

    // RES computed exactly as the reference does (double precision on host).
    double growth = exp((log(512.0) - log(16.0)) / 15.0);
    double res = pow(growth, 8.0) * 16.0;
    float scale = (float)(res - 1.0);

    int block = 256;
    int grid = (N_POINTS + block - 1) / block;  // 8192 blocks
    hashgrid_interp_kernel<<<grid, block, 0, stream>>>(X, table, out, scale);
}